// Round 5
// baseline (442.743 us; speedup 1.0000x reference)
//
#include <hip/hip_runtime.h>

#define NN 128

// 15 (l, pair) entries in reference order:
// l=0: (0,0),(1,1),(2,2)
// l=1: (0,1),(1,0),(1,1),(1,2),(2,1),(2,2)
// l=2: (0,2),(1,1),(1,2),(2,0),(2,1),(2,2)
__constant__ int E_l [15] = {0,0,0, 1,1,1,1,1,1, 2,2,2,2,2,2};
__constant__ int E_l1[15] = {0,1,2, 0,1,1,1,2,2, 0,1,1,2,2,2};
__constant__ int E_l2[15] = {0,1,2, 1,0,1,2,1,2, 2,1,2,0,1,2};
__constant__ int E_cg[15] = {0,1,10, 35,44,53,80,125,170, 245,270,315,390,415,490};
__constant__ int E_t [15] = {0,16,32, 48,96,144,192,240,288, 336,416,496,576,656,736};

__device__ __forceinline__ double dfact(int n){
    const double F[9] = {1.0,1.0,2.0,6.0,24.0,120.0,720.0,5040.0,40320.0};
    return F[n];
}

__device__ float cg_single(int j1,int m1,int j2,int m2,int j,int m){
    if (m1 + m2 != m) return 0.0f;
    double pre = sqrt((2.0*j+1.0)*dfact(j+j1-j2)*dfact(j-j1+j2)*dfact(j1+j2-j)/dfact(j1+j2+j+1));
    pre *= sqrt(dfact(j+m)*dfact(j-m)*dfact(j1-m1)*dfact(j1+m1)*dfact(j2-m2)*dfact(j2+m2));
    int k0 = 0;
    if (j2-j-m1 > k0) k0 = j2-j-m1;
    if (j1+m2-j > k0) k0 = j1+m2-j;
    int k1 = j1+j2-j;
    if (j1-m1 < k1) k1 = j1-m1;
    if (j2+m2 < k1) k1 = j2+m2;
    double s = 0.0;
    for (int k = k0; k <= k1; ++k){
        double d = dfact(k)*dfact(j1+j2-j-k)*dfact(j1-m1-k)*dfact(j2+m2-k)*dfact(j-j2+m1+k)*dfact(j-j1-m2+k);
        s += ((k & 1) ? -1.0 : 1.0) / d;
    }
    return (float)(pre * s);
}

// blob (float* base) layout: CG f32[615] @0 | TB u16[816] @byte 2464 | TA u8[160] @4096 | TC u16[160] @4256
// TB packs c(4) | st(8)<<4 | ct(4)<<12 ; TA packs a_idx(4)<<4 | b_idx(4) ; TC = CG flat index.

// k_setup: bid 0 -> build CG + term tables; bid 1..15 -> wrsum (sum_d of Wr rows)
__global__ __launch_bounds__(512) void k_setup(const float* __restrict__ Wr0, const float* __restrict__ Wr1,
                                               const float* __restrict__ Wr2,
                                               float* __restrict__ blob, float* __restrict__ wrsum){
    int bx = blockIdx.x, t = threadIdx.x;
    if (bx == 0){
        for (int idx = t; idx < 615; idx += 512){
            int e = 0;
            while (e < 14 && idx >= E_cg[e+1]) e++;
            int l = E_l[e], l1 = E_l1[e], l2 = E_l2[e];
            int local = idx - E_cg[e];
            int dl = 2*l+1, d2 = 2*l2+1;
            int k  = local % dl;
            int r  = local / dl;
            int u  = r % d2;
            int i1 = r / d2;
            blob[idx] = cg_single(l1, i1-l1, l2, u-l2, l, k-l);
        }
        if (t == 0){
            unsigned short* bTB = (unsigned short*)((char*)blob + 2464);
            unsigned char*  bTA = (unsigned char*)((char*)blob + 4096);
            unsigned short* bTC = (unsigned short*)((char*)blob + 4256);
            const int abase[3] = {0,1,4};
            int nt = 0;
            for (int e = 0; e < 15; ++e){
                int l = E_l[e], l1 = E_l1[e], l2 = E_l2[e];
                int dl = 2*l+1, d2 = 2*l2+1;
                for (int k = 0; k < dl; ++k){
                    int st = nt;
                    for (int m = 0; m < 2*l1+1; ++m){
                        int u = k - l + l1 + l2 - m;
                        if (u >= 0 && u <= 2*l2){
                            bTA[nt] = (unsigned char)(((abase[l1]+m)<<4) | (abase[l2]+u));
                            bTC[nt] = (unsigned short)(E_cg[e] + (m*d2+u)*dl + k);
                            nt++;
                        }
                    }
                    int ct = nt - st;
                    for (int c = 0; c < 16; ++c)
                        bTB[E_t[e] + k*16 + c] = (unsigned short)(c | (st<<4) | (ct<<12));
                }
            }
        }
        return;
    }
    int q = (bx-1)*512 + t;          // 7680 total
    int layer = q / 3840;
    int r = q % 3840;
    int row = r >> 4, co = r & 15;
    const float* Wr; int pairs; int lrow;
    if (row < 48)       { Wr = Wr0; pairs = 3; lrow = row; }
    else if (row < 144) { Wr = Wr1; pairs = 6; lrow = row - 48; }
    else                { Wr = Wr2; pairs = 6; lrow = row - 144; }
    int pairIdx = lrow >> 4, c = lrow & 15;
    const float* base = Wr + (size_t)layer*pairs*4096 + (size_t)(pairIdx*256 + c*16)*16 + co;
    float s = 0.f;
    #pragma unroll
    for (int d = 0; d < 16; ++d) s += base[d*16];
    wrsum[q] = s;
}

__device__ __forceinline__ void ld_tables(const float* __restrict__ blob, float* CG, unsigned short* TB,
                                          unsigned char* TA, unsigned short* TC, int t){
    for (int i = t; i < 615; i += 512) CG[i] = blob[i];
    const unsigned short* bTB = (const unsigned short*)((const char*)blob + 2464);
    for (int i = t; i < 816; i += 512) TB[i] = bTB[i];
    const unsigned char* bTA = (const unsigned char*)((const char*)blob + 4096);
    if (t < 160) TA[t] = bTA[t];
    const unsigned short* bTC = (const unsigned short*)((const char*)blob + 4256);
    if (t < 160) TC[t] = bTC[t];
}

__device__ __forceinline__ void tfill_full(const float* __restrict__ A, const float* __restrict__ S,
                                           const float* __restrict__ CG, const unsigned short* __restrict__ TB,
                                           const unsigned char* __restrict__ TA, const unsigned short* __restrict__ TC,
                                           float* __restrict__ Tw, int lane){
    for (int idx = lane; idx < 816; idx += 64){
        unsigned tbv = TB[idx];
        int c = tbv & 15, st = (tbv>>4) & 255, ct = tbv >> 12;
        float s = 0.f;
        for (int q = 0; q < ct; ++q){
            int ab = TA[st+q];
            s += A[(ab>>4)*16 + c] * S[ab & 15] * CG[TC[st+q]];
        }
        Tw[idx] = s;
    }
}

__device__ __forceinline__ void tfill_diag(const float* __restrict__ M,
                                           const float* __restrict__ CG, const unsigned short* __restrict__ TB,
                                           const unsigned char* __restrict__ TA, const unsigned short* __restrict__ TC,
                                           float* __restrict__ Tw, int lane){
    for (int idx = lane; idx < 816; idx += 64){
        unsigned tbv = TB[idx];
        int c = tbv & 15, st = (tbv>>4) & 255, ct = tbv >> 12;
        float s = 0.f;
        for (int q = 0; q < ct; ++q){
            int ab = TA[st+q];
            s += M[(ab>>4)*16 + c] * M[(ab&15)*16 + c] * CG[TC[st+q]];
        }
        Tw[idx] = s;
    }
}

__device__ __forceinline__ float mix_out(const float* __restrict__ WT, const float* __restrict__ Tw, int o){
    int krow = o >> 4, co = o & 15;
    int l = krow == 0 ? 0 : (krow < 4 ? 1 : 2);
    int k = krow - (l==0?0:(l==1?1:4));
    int np = l==0?3:6;
    int tb = l==0?0:(l==1?48:336);
    int rb = l==0?0:(l==1?48:144);
    int dl = 2*l+1;
    float acc = 0.f;
    const float4* Wp = (const float4*)&WT[co*244 + rb];
    for (int pq = 0; pq < np; ++pq){
        const float4* Tp = (const float4*)&Tw[tb + (pq*dl + k)*16];
        float4 a0=Tp[0],a1=Tp[1],a2=Tp[2],a3=Tp[3];
        float4 b0=Wp[pq*4],b1=Wp[pq*4+1],b2=Wp[pq*4+2],b3=Wp[pq*4+3];
        acc += a0.x*b0.x+a0.y*b0.y+a0.z*b0.z+a0.w*b0.w
             + a1.x*b1.x+a1.y*b1.y+a1.z*b1.z+a1.w*b1.w
             + a2.x*b2.x+a2.y*b2.y+a2.z*b2.z+a2.w*b2.w
             + a3.x*b3.x+a3.y*b3.y+a3.z*b3.z+a3.w*b3.w;
    }
    return acc;
}

// K1: layer-0 rel. 8 nodes/block, wave per node. Also emits sphx to ws.
__global__ __launch_bounds__(512,4) void k_rel0(const float* __restrict__ v0, const float* __restrict__ v1,
                                                const float* __restrict__ v2, const float* __restrict__ rel_pos,
                                                const float* __restrict__ blob, const float* __restrict__ wrsumL,
                                                float* __restrict__ sphx_ws, float* __restrict__ rel){
    __shared__ float CG[616];
    __shared__ unsigned short TB[816];
    __shared__ unsigned char TA[160];
    __shared__ unsigned short TC[160];
    __shared__ float WT[16*244];
    __shared__ float AL[8][144];
    __shared__ float SX[8][12];
    __shared__ __align__(16) float TS[8][816];
    int t = threadIdx.x, w = t >> 6, lane = t & 63;
    int node0 = blockIdx.x * 8, node = node0 + w;
    ld_tables(blob, CG, TB, TA, TC, t);
    for (int i = t; i < 3840; i += 512) WT[(i&15)*244 + (i>>4)] = wrsumL[i];
    for (int i = t; i < 1152; i += 512){
        int n = i/144, o = i%144, nd = node0+n;
        float v;
        if (o < 16)      v = v0[(size_t)nd*16 + o];
        else if (o < 64) v = v1[(size_t)nd*48 + (o-16)];
        else             v = v2[(size_t)nd*80 + (o-64)];
        AL[n][o] = v;
    }
    {
        const float* rp = rel_pos + (size_t)node * (NN*3);
        float a[9];
        #pragma unroll
        for (int i = 0; i < 9; ++i) a[i] = 0.f;
        #pragma unroll
        for (int rr = 0; rr < 2; ++rr){
            int j = lane + rr*64;
            float x = rp[j*3], y = rp[j*3+1], z = rp[j*3+2];
            float rn = sqrtf(x*x+y*y+z*z) + 1e-6f;
            x /= rn; y /= rn; z /= rn;
            a[0] += 0.28209479f;
            a[1] += 0.48860251f*y; a[2] += 0.48860251f*z; a[3] += 0.48860251f*x;
            a[4] += 1.09254843f*x*y; a[5] += 1.09254843f*y*z;
            a[6] += 0.31539157f*(3.f*z*z-1.f);
            a[7] += 1.09254843f*x*z; a[8] += 0.54627422f*(x*x-y*y);
        }
        #pragma unroll
        for (int i = 0; i < 9; ++i){
            float vv = a[i];
            for (int off = 32; off; off >>= 1) vv += __shfl_down(vv, off, 64);
            if (lane == 0){ SX[w][i] = vv; sphx_ws[(size_t)node*9 + i] = vv; }
        }
    }
    __syncthreads();
    tfill_full(&AL[w][0], &SX[w][0], CG, TB, TA, TC, &TS[w][0], lane);
    __syncthreads();
    float* relw = rel + (size_t)node * 144;
    for (int o = lane; o < 144; o += 64) relw[o] = mix_out(WT, &TS[w][0], o);
}

// K2/K4: message pass + diag CG + Wn mix + per-block partial sums.
__global__ __launch_bounds__(512,4) void k_mp(const float* __restrict__ norms, const float* __restrict__ rel,
                                              const float* __restrict__ blob,
                                              const float* __restrict__ Wn0, const float* __restrict__ Wn1,
                                              const float* __restrict__ Wn2, int layer,
                                              float* __restrict__ nl, float* __restrict__ part){
    __shared__ float CG[616];
    __shared__ unsigned short TB[816];
    __shared__ unsigned char TA[160];
    __shared__ unsigned short TC[160];
    __shared__ float WT[16*244];
    __shared__ unsigned char C4[8][128];
    __shared__ float MP[8][144];
    __shared__ __align__(16) float TS[8][816];
    __shared__ float RED[24];
    int t = threadIdx.x, w = t >> 6, lane = t & 63;
    int node0 = blockIdx.x * 8, node = node0 + w;
    int b = node0 >> 7;
    ld_tables(blob, CG, TB, TA, TC, t);
    for (int i = t; i < 768;  i += 512) WT[(i&15)*244 + (i>>4)]        = Wn0[(size_t)layer*768  + i];
    for (int i = t; i < 1536; i += 512) WT[(i&15)*244 + 48  + (i>>4)]  = Wn1[(size_t)layer*1536 + i];
    for (int i = t; i < 1536; i += 512) WT[(i&15)*244 + 144 + (i>>4)]  = Wn2[(size_t)layer*1536 + i];
    for (int i = t; i < 1024; i += 512){
        int n = i >> 7, j = i & 127;
        C4[n][j] = (norms[(size_t)(node0+n)*NN + j] < 0.5f) ? 1 : 0;
    }
    const float4* r4 = (const float4*)(rel + (size_t)b * NN * 144);
    float4 pA[4], pB[4], pC[4];
    #pragma unroll
    for (int r = 0; r < 4; ++r){
        pA[r] = r4[1152*r + t];
        pB[r] = r4[1152*r + 512 + t];
        pC[r] = (t < 128) ? r4[1152*r + 1024 + t] : make_float4(0.f,0.f,0.f,0.f);
    }
    float a0 = 0.f, a1 = 0.f, a2 = 0.f;
    float4* s4 = (float4*)&TS[0][0];
    #pragma unroll
    for (int r = 0; r < 4; ++r){
        __syncthreads();
        s4[t] = pA[r]; s4[512+t] = pB[r]; if (t < 128) s4[1024+t] = pC[r];
        __syncthreads();
        const unsigned* cw = (const unsigned*)&C4[w][r*32];
        const float* base = &TS[0][0];
        #pragma unroll
        for (int jq = 0; jq < 8; ++jq){
            unsigned cword = cw[jq];
            #pragma unroll
            for (int jb = 0; jb < 4; ++jb){
                float cn = (float)((cword >> (jb*8)) & 255u);
                const float* row = base + (jq*4+jb)*144;
                a0 += cn * row[lane];
                a1 += cn * row[64 + lane];
                if (lane < 16) a2 += cn * row[128 + lane];
            }
        }
    }
    MP[w][lane] = a0; MP[w][64+lane] = a1; if (lane < 16) MP[w][128+lane] = a2;
    __syncthreads();
    tfill_diag(&MP[w][0], CG, TB, TA, TC, &TS[w][0], lane);
    __syncthreads();
    float pz0 = 0.f, pz1 = 0.f, pz2 = 0.f;
    float* nlw = nl + (size_t)node * 144;
    for (int o = lane; o < 144; o += 64){
        float acc = mix_out(WT, &TS[w][0], o);
        nlw[o] = acc;
        float sq = acc*acc;
        int krow = o >> 4;
        if (krow == 0) pz0 += sq; else if (krow < 4) pz1 += sq; else pz2 += sq;
    }
    for (int off = 32; off; off >>= 1){
        pz0 += __shfl_down(pz0, off, 64);
        pz1 += __shfl_down(pz1, off, 64);
        pz2 += __shfl_down(pz2, off, 64);
    }
    if (lane == 0){ RED[w] = pz0; RED[8+w] = pz1; RED[16+w] = pz2; }
    __syncthreads();
    if (t < 3){
        float s = 0.f;
        #pragma unroll
        for (int q = 0; q < 8; ++q) s += RED[t*8 + q];
        part[blockIdx.x*4 + t] = s;
    }
}

// K3: normalize layer0 + scalars out + layer-1 rel.
__global__ __launch_bounds__(512,4) void k_eb(const float* __restrict__ blob, const float* __restrict__ wrsumL1,
                                              const float* __restrict__ part, const float* __restrict__ nl,
                                              const float* __restrict__ sphx_ws, float* __restrict__ rel,
                                              float* __restrict__ out){
    __shared__ float CG[616];
    __shared__ unsigned short TB[816];
    __shared__ unsigned char TA[160];
    __shared__ unsigned short TC[160];
    __shared__ float WT[16*244];
    __shared__ float AL[8][144];
    __shared__ float SX[8][12];
    __shared__ __align__(16) float TS[8][816];
    __shared__ float RED[24];
    __shared__ float SC[3];
    int t = threadIdx.x, w = t >> 6, lane = t & 63;
    int node0 = blockIdx.x * 8, node = node0 + w;
    ld_tables(blob, CG, TB, TA, TC, t);
    for (int i = t; i < 3840; i += 512) WT[(i&15)*244 + (i>>4)] = wrsumL1[i];
    {
        float q0 = part[t*4], q1 = part[t*4+1], q2 = part[t*4+2];
        for (int off = 32; off; off >>= 1){
            q0 += __shfl_down(q0, off, 64);
            q1 += __shfl_down(q1, off, 64);
            q2 += __shfl_down(q2, off, 64);
        }
        if (lane == 0){ RED[w] = q0; RED[8+w] = q1; RED[16+w] = q2; }
    }
    __syncthreads();
    if (t < 3){
        float s = 0.f;
        #pragma unroll
        for (int q = 0; q < 8; ++q) s += RED[t*8 + q];
        SC[t] = 16.f / ((2*t+1) * sqrtf(s));
    }
    __syncthreads();
    float sc0 = SC[0], sc1 = SC[1], sc2 = SC[2];
    for (int i = t; i < 1152; i += 512){
        int n = i/144, o = i%144, krow = o >> 4;
        float scl = krow == 0 ? sc0 : (krow < 4 ? sc1 : sc2);
        AL[n][o] = nl[(size_t)(node0+n)*144 + o] * scl;
    }
    if (t < 72) SX[t/9][t%9] = sphx_ws[(size_t)node0*9 + t];
    __syncthreads();
    if (t < 128){
        int n = t >> 4, c = t & 15;
        float s0 = AL[n][c];
        float sn0 = s0*s0, sn1 = 0.f, sn2 = 0.f;
        #pragma unroll
        for (int k = 0; k < 3; ++k){ float v = AL[n][16 + k*16 + c]; sn1 += v*v; }
        #pragma unroll
        for (int k = 0; k < 5; ++k){ float v = AL[n][64 + k*16 + c]; sn2 += v*v; }
        float* ob = out + (size_t)(node0+n)*128;
        ob[c] = s0; ob[16+c] = sn0; ob[32+c] = sn1; ob[48+c] = sn2;
    }
    tfill_full(&AL[w][0], &SX[w][0], CG, TB, TA, TC, &TS[w][0], lane);
    __syncthreads();
    float* relw = rel + (size_t)node * 144;
    for (int o = lane; o < 144; o += 64) relw[o] = mix_out(WT, &TS[w][0], o);
}

// K5: normalize layer1 + scalars out.
__global__ __launch_bounds__(512) void k_e2(const float* __restrict__ part, const float* __restrict__ nl,
                                            float* __restrict__ out){
    __shared__ float RED[24];
    __shared__ float SC[3];
    __shared__ float VV[8][144];
    int t = threadIdx.x, w = t >> 6, lane = t & 63;
    int node0 = blockIdx.x * 8;
    {
        float q0 = part[t*4], q1 = part[t*4+1], q2 = part[t*4+2];
        for (int off = 32; off; off >>= 1){
            q0 += __shfl_down(q0, off, 64);
            q1 += __shfl_down(q1, off, 64);
            q2 += __shfl_down(q2, off, 64);
        }
        if (lane == 0){ RED[w] = q0; RED[8+w] = q1; RED[16+w] = q2; }
    }
    __syncthreads();
    if (t < 3){
        float s = 0.f;
        #pragma unroll
        for (int q = 0; q < 8; ++q) s += RED[t*8 + q];
        SC[t] = 16.f / ((2*t+1) * sqrtf(s));
    }
    __syncthreads();
    float sc0 = SC[0], sc1 = SC[1], sc2 = SC[2];
    for (int i = t; i < 1152; i += 512){
        int n = i/144, o = i%144, krow = o >> 4;
        float scl = krow == 0 ? sc0 : (krow < 4 ? sc1 : sc2);
        VV[n][o] = nl[(size_t)(node0+n)*144 + o] * scl;
    }
    __syncthreads();
    if (t < 128){
        int n = t >> 4, c = t & 15;
        float s0 = VV[n][c];
        float sn0 = s0*s0, sn1 = 0.f, sn2 = 0.f;
        #pragma unroll
        for (int k = 0; k < 3; ++k){ float v = VV[n][16 + k*16 + c]; sn1 += v*v; }
        #pragma unroll
        for (int k = 0; k < 5; ++k){ float v = VV[n][64 + k*16 + c]; sn2 += v*v; }
        float* ob = out + (size_t)(node0+n)*128 + 64;
        ob[c] = s0; ob[16+c] = sn0; ob[32+c] = sn1; ob[48+c] = sn2;
    }
}

extern "C" void kernel_launch(void* const* d_in, const int* in_sizes, int n_in,
                              void* d_out, int out_size, void* d_ws, size_t ws_size,
                              hipStream_t stream){
    const float* v0      = (const float*)d_in[0];
    const float* v1      = (const float*)d_in[1];
    const float* v2      = (const float*)d_in[2];
    const float* rel_pos = (const float*)d_in[3];
    const float* norms   = (const float*)d_in[4];
    const float* Wr0     = (const float*)d_in[5];
    const float* Wr1     = (const float*)d_in[6];
    const float* Wr2     = (const float*)d_in[7];
    const float* Wn0     = (const float*)d_in[8];
    const float* Wn1     = (const float*)d_in[9];
    const float* Wn2     = (const float*)d_in[10];
    float* out = (float*)d_out;
    float* ws  = (float*)d_ws;

    // ws layout (float offsets)
    float* blob  = ws + 0;        // 1152 (4608 B: CG+TB+TA+TC)
    float* wrsum = ws + 1152;     // 7680
    float* sphx  = ws + 8832;     // 4096*9 = 36864
    float* rel   = ws + 45696;    // 4096*144 = 589824
    float* nl    = ws + 635520;   // 4096*144 = 589824
    float* part  = ws + 1225344;  // 512*4 = 2048

    k_setup<<<16, 512, 0, stream>>>(Wr0, Wr1, Wr2, blob, wrsum);
    k_rel0 <<<512, 512, 0, stream>>>(v0, v1, v2, rel_pos, blob, wrsum, sphx, rel);
    k_mp   <<<512, 512, 0, stream>>>(norms, rel, blob, Wn0, Wn1, Wn2, 0, nl, part);
    k_eb   <<<512, 512, 0, stream>>>(blob, wrsum + 3840, part, nl, sphx, rel, out);
    k_mp   <<<512, 512, 0, stream>>>(norms, rel, blob, Wn0, Wn1, Wn2, 1, nl, part);
    k_e2   <<<512, 512, 0, stream>>>(part, nl, out);
}

// Round 6
// 429.846 us; speedup vs baseline: 1.0300x; 1.0300x over previous
//
#include <hip/hip_runtime.h>

#define NN 128

// 15 (l, pair) entries in reference order:
// l=0: (0,0),(1,1),(2,2)
// l=1: (0,1),(1,0),(1,1),(1,2),(2,1),(2,2)
// l=2: (0,2),(1,1),(1,2),(2,0),(2,1),(2,2)
__constant__ int E_l [15] = {0,0,0, 1,1,1,1,1,1, 2,2,2,2,2,2};
__constant__ int E_l1[15] = {0,1,2, 0,1,1,1,2,2, 0,1,1,2,2,2};
__constant__ int E_l2[15] = {0,1,2, 1,0,1,2,1,2, 2,1,2,0,1,2};
__constant__ int E_cg[15] = {0,1,10, 35,44,53,80,125,170, 245,270,315,390,415,490};
__constant__ int E_t [15] = {0,16,32, 48,96,144,192,240,288, 336,416,496,576,656,736};

__device__ __forceinline__ double dfact(int n){
    const double F[9] = {1.0,1.0,2.0,6.0,24.0,120.0,720.0,5040.0,40320.0};
    return F[n];
}

__device__ float cg_single(int j1,int m1,int j2,int m2,int j,int m){
    if (m1 + m2 != m) return 0.0f;
    double pre = sqrt((2.0*j+1.0)*dfact(j+j1-j2)*dfact(j-j1+j2)*dfact(j1+j2-j)/dfact(j1+j2+j+1));
    pre *= sqrt(dfact(j+m)*dfact(j-m)*dfact(j1-m1)*dfact(j1+m1)*dfact(j2-m2)*dfact(j2+m2));
    int k0 = 0;
    if (j2-j-m1 > k0) k0 = j2-j-m1;
    if (j1+m2-j > k0) k0 = j1+m2-j;
    int k1 = j1+j2-j;
    if (j1-m1 < k1) k1 = j1-m1;
    if (j2+m2 < k1) k1 = j2+m2;
    double s = 0.0;
    for (int k = k0; k <= k1; ++k){
        double d = dfact(k)*dfact(j1+j2-j-k)*dfact(j1-m1-k)*dfact(j2+m2-k)*dfact(j-j2+m1+k)*dfact(j-j1-m2+k);
        s += ((k & 1) ? -1.0 : 1.0) / d;
    }
    return (float)(pre * s);
}

// blob (float* base) layout: CG f32[615] @0 | TB u16[816] @byte 2464 | TA u8[160] @4096 | TC u16[160] @4256
// TB packs c(4) | st(8)<<4 | ct(4)<<12 ; TA packs a_idx(4)<<4 | b_idx(4) ; TC = CG flat index.

// k_setup: bid 0 -> build CG + term tables; bid 1..15 -> wrsum (sum_d of Wr rows)
__global__ __launch_bounds__(512) void k_setup(const float* __restrict__ Wr0, const float* __restrict__ Wr1,
                                               const float* __restrict__ Wr2,
                                               float* __restrict__ blob, float* __restrict__ wrsum){
    int bx = blockIdx.x, t = threadIdx.x;
    if (bx == 0){
        for (int idx = t; idx < 615; idx += 512){
            int e = 0;
            while (e < 14 && idx >= E_cg[e+1]) e++;
            int l = E_l[e], l1 = E_l1[e], l2 = E_l2[e];
            int local = idx - E_cg[e];
            int dl = 2*l+1, d2 = 2*l2+1;
            int k  = local % dl;
            int r  = local / dl;
            int u  = r % d2;
            int i1 = r / d2;
            blob[idx] = cg_single(l1, i1-l1, l2, u-l2, l, k-l);
        }
        if (t == 0){
            unsigned short* bTB = (unsigned short*)((char*)blob + 2464);
            unsigned char*  bTA = (unsigned char*)((char*)blob + 4096);
            unsigned short* bTC = (unsigned short*)((char*)blob + 4256);
            const int abase[3] = {0,1,4};
            int nt = 0;
            for (int e = 0; e < 15; ++e){
                int l = E_l[e], l1 = E_l1[e], l2 = E_l2[e];
                int dl = 2*l+1, d2 = 2*l2+1;
                for (int k = 0; k < dl; ++k){
                    int st = nt;
                    for (int m = 0; m < 2*l1+1; ++m){
                        int u = k - l + l1 + l2 - m;
                        if (u >= 0 && u <= 2*l2){
                            bTA[nt] = (unsigned char)(((abase[l1]+m)<<4) | (abase[l2]+u));
                            bTC[nt] = (unsigned short)(E_cg[e] + (m*d2+u)*dl + k);
                            nt++;
                        }
                    }
                    int ct = nt - st;
                    for (int c = 0; c < 16; ++c)
                        bTB[E_t[e] + k*16 + c] = (unsigned short)(c | (st<<4) | (ct<<12));
                }
            }
        }
        return;
    }
    int q = (bx-1)*512 + t;          // 7680 total
    int layer = q / 3840;
    int r = q % 3840;
    int row = r >> 4, co = r & 15;
    const float* Wr; int pairs; int lrow;
    if (row < 48)       { Wr = Wr0; pairs = 3; lrow = row; }
    else if (row < 144) { Wr = Wr1; pairs = 6; lrow = row - 48; }
    else                { Wr = Wr2; pairs = 6; lrow = row - 144; }
    int pairIdx = lrow >> 4, c = lrow & 15;
    const float* base = Wr + (size_t)layer*pairs*4096 + (size_t)(pairIdx*256 + c*16)*16 + co;
    float s = 0.f;
    #pragma unroll
    for (int d = 0; d < 16; ++d) s += base[d*16];
    wrsum[q] = s;
}

__device__ __forceinline__ void ld_tables(const float* __restrict__ blob, float* CG, unsigned short* TB,
                                          unsigned char* TA, unsigned short* TC, int t){
    for (int i = t; i < 615; i += 512) CG[i] = blob[i];
    const unsigned short* bTB = (const unsigned short*)((const char*)blob + 2464);
    for (int i = t; i < 816; i += 512) TB[i] = bTB[i];
    const unsigned char* bTA = (const unsigned char*)((const char*)blob + 4096);
    if (t < 160) TA[t] = bTA[t];
    const unsigned short* bTC = (const unsigned short*)((const char*)blob + 4256);
    if (t < 160) TC[t] = bTC[t];
}

__device__ __forceinline__ void tfill_full(const float* __restrict__ A, const float* __restrict__ S,
                                           const float* __restrict__ CG, const unsigned short* __restrict__ TB,
                                           const unsigned char* __restrict__ TA, const unsigned short* __restrict__ TC,
                                           float* __restrict__ Tw, int lane){
    for (int idx = lane; idx < 816; idx += 64){
        unsigned tbv = TB[idx];
        int c = tbv & 15, st = (tbv>>4) & 255, ct = tbv >> 12;
        float s = 0.f;
        for (int q = 0; q < ct; ++q){
            int ab = TA[st+q];
            s += A[(ab>>4)*16 + c] * S[ab & 15] * CG[TC[st+q]];
        }
        Tw[idx] = s;
    }
}

__device__ __forceinline__ void tfill_diag(const float* __restrict__ M,
                                           const float* __restrict__ CG, const unsigned short* __restrict__ TB,
                                           const unsigned char* __restrict__ TA, const unsigned short* __restrict__ TC,
                                           float* __restrict__ Tw, int lane){
    for (int idx = lane; idx < 816; idx += 64){
        unsigned tbv = TB[idx];
        int c = tbv & 15, st = (tbv>>4) & 255, ct = tbv >> 12;
        float s = 0.f;
        for (int q = 0; q < ct; ++q){
            int ab = TA[st+q];
            s += M[(ab>>4)*16 + c] * M[(ab&15)*16 + c] * CG[TC[st+q]];
        }
        Tw[idx] = s;
    }
}

__device__ __forceinline__ float mix_out(const float* __restrict__ WT, const float* __restrict__ Tw, int o){
    int krow = o >> 4, co = o & 15;
    int l = krow == 0 ? 0 : (krow < 4 ? 1 : 2);
    int k = krow - (l==0?0:(l==1?1:4));
    int np = l==0?3:6;
    int tb = l==0?0:(l==1?48:336);
    int rb = l==0?0:(l==1?48:144);
    int dl = 2*l+1;
    float acc = 0.f;
    const float4* Wp = (const float4*)&WT[co*244 + rb];
    for (int pq = 0; pq < np; ++pq){
        const float4* Tp = (const float4*)&Tw[tb + (pq*dl + k)*16];
        float4 a0=Tp[0],a1=Tp[1],a2=Tp[2],a3=Tp[3];
        float4 b0=Wp[pq*4],b1=Wp[pq*4+1],b2=Wp[pq*4+2],b3=Wp[pq*4+3];
        acc += a0.x*b0.x+a0.y*b0.y+a0.z*b0.z+a0.w*b0.w
             + a1.x*b1.x+a1.y*b1.y+a1.z*b1.z+a1.w*b1.w
             + a2.x*b2.x+a2.y*b2.y+a2.z*b2.z+a2.w*b2.w
             + a3.x*b3.x+a3.y*b3.y+a3.z*b3.z+a3.w*b3.w;
    }
    return acc;
}

// K1: layer-0 rel. 8 nodes/block, wave per node. Also emits sphx to ws.
__global__ __launch_bounds__(512,4) void k_rel0(const float* __restrict__ v0, const float* __restrict__ v1,
                                                const float* __restrict__ v2, const float* __restrict__ rel_pos,
                                                const float* __restrict__ blob, const float* __restrict__ wrsumL,
                                                float* __restrict__ sphx_ws, float* __restrict__ rel){
    __shared__ float CG[616];
    __shared__ unsigned short TB[816];
    __shared__ unsigned char TA[160];
    __shared__ unsigned short TC[160];
    __shared__ float WT[16*244];
    __shared__ float AL[8][144];
    __shared__ float SX[8][12];
    __shared__ __align__(16) float TS[8][816];
    int t = threadIdx.x, w = t >> 6, lane = t & 63;
    int node0 = blockIdx.x * 8, node = node0 + w;
    ld_tables(blob, CG, TB, TA, TC, t);
    for (int i = t; i < 3840; i += 512) WT[(i&15)*244 + (i>>4)] = wrsumL[i];
    for (int i = t; i < 1152; i += 512){
        int n = i/144, o = i%144, nd = node0+n;
        float v;
        if (o < 16)      v = v0[(size_t)nd*16 + o];
        else if (o < 64) v = v1[(size_t)nd*48 + (o-16)];
        else             v = v2[(size_t)nd*80 + (o-64)];
        AL[n][o] = v;
    }
    {
        const float* rp = rel_pos + (size_t)node * (NN*3);
        float a[9];
        #pragma unroll
        for (int i = 0; i < 9; ++i) a[i] = 0.f;
        #pragma unroll
        for (int rr = 0; rr < 2; ++rr){
            int j = lane + rr*64;
            float x = rp[j*3], y = rp[j*3+1], z = rp[j*3+2];
            float rn = sqrtf(x*x+y*y+z*z) + 1e-6f;
            x /= rn; y /= rn; z /= rn;
            a[0] += 0.28209479f;
            a[1] += 0.48860251f*y; a[2] += 0.48860251f*z; a[3] += 0.48860251f*x;
            a[4] += 1.09254843f*x*y; a[5] += 1.09254843f*y*z;
            a[6] += 0.31539157f*(3.f*z*z-1.f);
            a[7] += 1.09254843f*x*z; a[8] += 0.54627422f*(x*x-y*y);
        }
        #pragma unroll
        for (int i = 0; i < 9; ++i){
            float vv = a[i];
            for (int off = 32; off; off >>= 1) vv += __shfl_down(vv, off, 64);
            if (lane == 0){ SX[w][i] = vv; sphx_ws[(size_t)node*9 + i] = vv; }
        }
    }
    __syncthreads();
    tfill_full(&AL[w][0], &SX[w][0], CG, TB, TA, TC, &TS[w][0], lane);
    __syncthreads();
    float* relw = rel + (size_t)node * 144;
    for (int o = lane; o < 144; o += 64) relw[o] = mix_out(WT, &TS[w][0], o);
}

// K2/K4: message pass + diag CG + Wn mix + per-block partial sums.
// Rolling 1-round register prefetch (3 float4 = 12 VGPRs live) -> no scratch spill.
__global__ __launch_bounds__(512,4) void k_mp(const float* __restrict__ norms, const float* __restrict__ rel,
                                              const float* __restrict__ blob,
                                              const float* __restrict__ Wn0, const float* __restrict__ Wn1,
                                              const float* __restrict__ Wn2, int layer,
                                              float* __restrict__ nl, float* __restrict__ part){
    __shared__ float CG[616];
    __shared__ unsigned short TB[816];
    __shared__ unsigned char TA[160];
    __shared__ unsigned short TC[160];
    __shared__ float WT[16*244];
    __shared__ unsigned char C4[8][128];
    __shared__ float MP[8][144];
    __shared__ __align__(16) float TS[8][816];
    __shared__ float RED[24];
    int t = threadIdx.x, w = t >> 6, lane = t & 63;
    int node0 = blockIdx.x * 8, node = node0 + w;
    int b = node0 >> 7;
    ld_tables(blob, CG, TB, TA, TC, t);
    for (int i = t; i < 768;  i += 512) WT[(i&15)*244 + (i>>4)]        = Wn0[(size_t)layer*768  + i];
    for (int i = t; i < 1536; i += 512) WT[(i&15)*244 + 48  + (i>>4)]  = Wn1[(size_t)layer*1536 + i];
    for (int i = t; i < 1536; i += 512) WT[(i&15)*244 + 144 + (i>>4)]  = Wn2[(size_t)layer*1536 + i];
    for (int i = t; i < 1024; i += 512){
        int n = i >> 7, j = i & 127;
        C4[n][j] = (norms[(size_t)(node0+n)*NN + j] < 0.5f) ? 1 : 0;
    }
    const float4* r4 = (const float4*)(rel + (size_t)b * NN * 144);
    // round 0 prefetch (registers): 3 float4 per thread max
    float4 rA = r4[t];
    float4 rB = r4[512 + t];
    float4 rC = (t < 128) ? r4[1024 + t] : make_float4(0.f,0.f,0.f,0.f);
    float a0 = 0.f, a1 = 0.f, a2 = 0.f;
    float4* s4 = (float4*)&TS[0][0];
    #pragma unroll
    for (int r = 0; r < 4; ++r){
        __syncthreads();
        s4[t] = rA; s4[512+t] = rB; if (t < 128) s4[1024+t] = rC;
        __syncthreads();
        if (r < 3){
            rA = r4[(r+1)*1152 + t];
            rB = r4[(r+1)*1152 + 512 + t];
            if (t < 128) rC = r4[(r+1)*1152 + 1024 + t];
        }
        const unsigned* cw = (const unsigned*)&C4[w][r*32];
        const float* base = &TS[0][0];
        #pragma unroll
        for (int jq = 0; jq < 8; ++jq){
            unsigned cword = cw[jq];
            #pragma unroll
            for (int jb = 0; jb < 4; ++jb){
                float cn = (float)((cword >> (jb*8)) & 255u);
                const float* row = base + (jq*4+jb)*144;
                a0 += cn * row[lane];
                a1 += cn * row[64 + lane];
                if (lane < 16) a2 += cn * row[128 + lane];
            }
        }
    }
    __syncthreads();
    MP[w][lane] = a0; MP[w][64+lane] = a1; if (lane < 16) MP[w][128+lane] = a2;
    __syncthreads();
    tfill_diag(&MP[w][0], CG, TB, TA, TC, &TS[w][0], lane);
    __syncthreads();
    float pz0 = 0.f, pz1 = 0.f, pz2 = 0.f;
    float* nlw = nl + (size_t)node * 144;
    for (int o = lane; o < 144; o += 64){
        float acc = mix_out(WT, &TS[w][0], o);
        nlw[o] = acc;
        float sq = acc*acc;
        int krow = o >> 4;
        if (krow == 0) pz0 += sq; else if (krow < 4) pz1 += sq; else pz2 += sq;
    }
    for (int off = 32; off; off >>= 1){
        pz0 += __shfl_down(pz0, off, 64);
        pz1 += __shfl_down(pz1, off, 64);
        pz2 += __shfl_down(pz2, off, 64);
    }
    if (lane == 0){ RED[w] = pz0; RED[8+w] = pz1; RED[16+w] = pz2; }
    __syncthreads();
    if (t < 3){
        float s = 0.f;
        #pragma unroll
        for (int q = 0; q < 8; ++q) s += RED[t*8 + q];
        part[blockIdx.x*4 + t] = s;
    }
}

// K3: normalize layer0 + scalars out + layer-1 rel.
__global__ __launch_bounds__(512,4) void k_eb(const float* __restrict__ blob, const float* __restrict__ wrsumL1,
                                              const float* __restrict__ part, const float* __restrict__ nl,
                                              const float* __restrict__ sphx_ws, float* __restrict__ rel,
                                              float* __restrict__ out){
    __shared__ float CG[616];
    __shared__ unsigned short TB[816];
    __shared__ unsigned char TA[160];
    __shared__ unsigned short TC[160];
    __shared__ float WT[16*244];
    __shared__ float AL[8][144];
    __shared__ float SX[8][12];
    __shared__ __align__(16) float TS[8][816];
    __shared__ float RED[24];
    __shared__ float SC[3];
    int t = threadIdx.x, w = t >> 6, lane = t & 63;
    int node0 = blockIdx.x * 8, node = node0 + w;
    ld_tables(blob, CG, TB, TA, TC, t);
    for (int i = t; i < 3840; i += 512) WT[(i&15)*244 + (i>>4)] = wrsumL1[i];
    {
        float q0 = part[t*4], q1 = part[t*4+1], q2 = part[t*4+2];
        for (int off = 32; off; off >>= 1){
            q0 += __shfl_down(q0, off, 64);
            q1 += __shfl_down(q1, off, 64);
            q2 += __shfl_down(q2, off, 64);
        }
        if (lane == 0){ RED[w] = q0; RED[8+w] = q1; RED[16+w] = q2; }
    }
    __syncthreads();
    if (t < 3){
        float s = 0.f;
        #pragma unroll
        for (int q = 0; q < 8; ++q) s += RED[t*8 + q];
        SC[t] = 16.f / ((2*t+1) * sqrtf(s));
    }
    __syncthreads();
    float sc0 = SC[0], sc1 = SC[1], sc2 = SC[2];
    for (int i = t; i < 1152; i += 512){
        int n = i/144, o = i%144, krow = o >> 4;
        float scl = krow == 0 ? sc0 : (krow < 4 ? sc1 : sc2);
        AL[n][o] = nl[(size_t)(node0+n)*144 + o] * scl;
    }
    if (t < 72) SX[t/9][t%9] = sphx_ws[(size_t)node0*9 + t];
    __syncthreads();
    if (t < 128){
        int n = t >> 4, c = t & 15;
        float s0 = AL[n][c];
        float sn0 = s0*s0, sn1 = 0.f, sn2 = 0.f;
        #pragma unroll
        for (int k = 0; k < 3; ++k){ float v = AL[n][16 + k*16 + c]; sn1 += v*v; }
        #pragma unroll
        for (int k = 0; k < 5; ++k){ float v = AL[n][64 + k*16 + c]; sn2 += v*v; }
        float* ob = out + (size_t)(node0+n)*128;
        ob[c] = s0; ob[16+c] = sn0; ob[32+c] = sn1; ob[48+c] = sn2;
    }
    tfill_full(&AL[w][0], &SX[w][0], CG, TB, TA, TC, &TS[w][0], lane);
    __syncthreads();
    float* relw = rel + (size_t)node * 144;
    for (int o = lane; o < 144; o += 64) relw[o] = mix_out(WT, &TS[w][0], o);
}

// K5: normalize layer1 + scalars out.
__global__ __launch_bounds__(512) void k_e2(const float* __restrict__ part, const float* __restrict__ nl,
                                            float* __restrict__ out){
    __shared__ float RED[24];
    __shared__ float SC[3];
    __shared__ float VV[8][144];
    int t = threadIdx.x, w = t >> 6, lane = t & 63;
    int node0 = blockIdx.x * 8;
    {
        float q0 = part[t*4], q1 = part[t*4+1], q2 = part[t*4+2];
        for (int off = 32; off; off >>= 1){
            q0 += __shfl_down(q0, off, 64);
            q1 += __shfl_down(q1, off, 64);
            q2 += __shfl_down(q2, off, 64);
        }
        if (lane == 0){ RED[w] = q0; RED[8+w] = q1; RED[16+w] = q2; }
    }
    __syncthreads();
    if (t < 3){
        float s = 0.f;
        #pragma unroll
        for (int q = 0; q < 8; ++q) s += RED[t*8 + q];
        SC[t] = 16.f / ((2*t+1) * sqrtf(s));
    }
    __syncthreads();
    float sc0 = SC[0], sc1 = SC[1], sc2 = SC[2];
    for (int i = t; i < 1152; i += 512){
        int n = i/144, o = i%144, krow = o >> 4;
        float scl = krow == 0 ? sc0 : (krow < 4 ? sc1 : sc2);
        VV[n][o] = nl[(size_t)(node0+n)*144 + o] * scl;
    }
    __syncthreads();
    if (t < 128){
        int n = t >> 4, c = t & 15;
        float s0 = VV[n][c];
        float sn0 = s0*s0, sn1 = 0.f, sn2 = 0.f;
        #pragma unroll
        for (int k = 0; k < 3; ++k){ float v = VV[n][16 + k*16 + c]; sn1 += v*v; }
        #pragma unroll
        for (int k = 0; k < 5; ++k){ float v = VV[n][64 + k*16 + c]; sn2 += v*v; }
        float* ob = out + (size_t)(node0+n)*128 + 64;
        ob[c] = s0; ob[16+c] = sn0; ob[32+c] = sn1; ob[48+c] = sn2;
    }
}

extern "C" void kernel_launch(void* const* d_in, const int* in_sizes, int n_in,
                              void* d_out, int out_size, void* d_ws, size_t ws_size,
                              hipStream_t stream){
    const float* v0      = (const float*)d_in[0];
    const float* v1      = (const float*)d_in[1];
    const float* v2      = (const float*)d_in[2];
    const float* rel_pos = (const float*)d_in[3];
    const float* norms   = (const float*)d_in[4];
    const float* Wr0     = (const float*)d_in[5];
    const float* Wr1     = (const float*)d_in[6];
    const float* Wr2     = (const float*)d_in[7];
    const float* Wn0     = (const float*)d_in[8];
    const float* Wn1     = (const float*)d_in[9];
    const float* Wn2     = (const float*)d_in[10];
    float* out = (float*)d_out;
    float* ws  = (float*)d_ws;

    // ws layout (float offsets)
    float* blob  = ws + 0;        // 1152 (4608 B: CG+TB+TA+TC)
    float* wrsum = ws + 1152;     // 7680
    float* sphx  = ws + 8832;     // 4096*9 = 36864
    float* rel   = ws + 45696;    // 4096*144 = 589824
    float* nl    = ws + 635520;   // 4096*144 = 589824
    float* part  = ws + 1225344;  // 512*4 = 2048

    k_setup<<<16, 512, 0, stream>>>(Wr0, Wr1, Wr2, blob, wrsum);
    k_rel0 <<<512, 512, 0, stream>>>(v0, v1, v2, rel_pos, blob, wrsum, sphx, rel);
    k_mp   <<<512, 512, 0, stream>>>(norms, rel, blob, Wn0, Wn1, Wn2, 0, nl, part);
    k_eb   <<<512, 512, 0, stream>>>(blob, wrsum + 3840, part, nl, sphx, rel, out);
    k_mp   <<<512, 512, 0, stream>>>(norms, rel, blob, Wn0, Wn1, Wn2, 1, nl, part);
    k_e2   <<<512, 512, 0, stream>>>(part, nl, out);
}

// Round 7
// 315.148 us; speedup vs baseline: 1.4049x; 1.3640x over previous
//
#include <hip/hip_runtime.h>

#define NN 128

// 15 (l, pair) entries in reference order:
// l=0: (0,0),(1,1),(2,2)
// l=1: (0,1),(1,0),(1,1),(1,2),(2,1),(2,2)
// l=2: (0,2),(1,1),(1,2),(2,0),(2,1),(2,2)
__constant__ int E_l [15] = {0,0,0, 1,1,1,1,1,1, 2,2,2,2,2,2};
__constant__ int E_l1[15] = {0,1,2, 0,1,1,1,2,2, 0,1,1,2,2,2};
__constant__ int E_l2[15] = {0,1,2, 1,0,1,2,1,2, 2,1,2,0,1,2};
__constant__ int E_cg[15] = {0,1,10, 35,44,53,80,125,170, 245,270,315,390,415,490};
__constant__ int E_t [15] = {0,16,32, 48,96,144,192,240,288, 336,416,496,576,656,736};

__device__ __forceinline__ double dfact(int n){
    const double F[9] = {1.0,1.0,2.0,6.0,24.0,120.0,720.0,5040.0,40320.0};
    return F[n];
}

__device__ float cg_single(int j1,int m1,int j2,int m2,int j,int m){
    if (m1 + m2 != m) return 0.0f;
    double pre = sqrt((2.0*j+1.0)*dfact(j+j1-j2)*dfact(j-j1+j2)*dfact(j1+j2-j)/dfact(j1+j2+j+1));
    pre *= sqrt(dfact(j+m)*dfact(j-m)*dfact(j1-m1)*dfact(j1+m1)*dfact(j2-m2)*dfact(j2+m2));
    int k0 = 0;
    if (j2-j-m1 > k0) k0 = j2-j-m1;
    if (j1+m2-j > k0) k0 = j1+m2-j;
    int k1 = j1+j2-j;
    if (j1-m1 < k1) k1 = j1-m1;
    if (j2+m2 < k1) k1 = j2+m2;
    double s = 0.0;
    for (int k = k0; k <= k1; ++k){
        double d = dfact(k)*dfact(j1+j2-j-k)*dfact(j1-m1-k)*dfact(j2+m2-k)*dfact(j-j2+m1+k)*dfact(j-j1-m2+k);
        s += ((k & 1) ? -1.0 : 1.0) / d;
    }
    return (float)(pre * s);
}

// blob (float* base) layout: CG f32[615] @0 | TB u16[816] @byte 2464 | TA u8[160] @4096 | TC u16[160] @4256
// TB packs c(4) | st(8)<<4 | ct(4)<<12 ; TA packs a_idx(4)<<4 | b_idx(4) ; TC = CG flat index.

// k_setup: bid 0 -> build CG + term tables; bid 1..15 -> wrsum (sum_d of Wr rows)
__global__ __launch_bounds__(512) void k_setup(const float* __restrict__ Wr0, const float* __restrict__ Wr1,
                                               const float* __restrict__ Wr2,
                                               float* __restrict__ blob, float* __restrict__ wrsum){
    int bx = blockIdx.x, t = threadIdx.x;
    if (bx == 0){
        for (int idx = t; idx < 615; idx += 512){
            int e = 0;
            while (e < 14 && idx >= E_cg[e+1]) e++;
            int l = E_l[e], l1 = E_l1[e], l2 = E_l2[e];
            int local = idx - E_cg[e];
            int dl = 2*l+1, d2 = 2*l2+1;
            int k  = local % dl;
            int r  = local / dl;
            int u  = r % d2;
            int i1 = r / d2;
            blob[idx] = cg_single(l1, i1-l1, l2, u-l2, l, k-l);
        }
        if (t == 0){
            unsigned short* bTB = (unsigned short*)((char*)blob + 2464);
            unsigned char*  bTA = (unsigned char*)((char*)blob + 4096);
            unsigned short* bTC = (unsigned short*)((char*)blob + 4256);
            const int abase[3] = {0,1,4};
            int nt = 0;
            for (int e = 0; e < 15; ++e){
                int l = E_l[e], l1 = E_l1[e], l2 = E_l2[e];
                int dl = 2*l+1, d2 = 2*l2+1;
                for (int k = 0; k < dl; ++k){
                    int st = nt;
                    for (int m = 0; m < 2*l1+1; ++m){
                        int u = k - l + l1 + l2 - m;
                        if (u >= 0 && u <= 2*l2){
                            bTA[nt] = (unsigned char)(((abase[l1]+m)<<4) | (abase[l2]+u));
                            bTC[nt] = (unsigned short)(E_cg[e] + (m*d2+u)*dl + k);
                            nt++;
                        }
                    }
                    int ct = nt - st;
                    for (int c = 0; c < 16; ++c)
                        bTB[E_t[e] + k*16 + c] = (unsigned short)(c | (st<<4) | (ct<<12));
                }
            }
        }
        return;
    }
    int q = (bx-1)*512 + t;          // 7680 total
    int layer = q / 3840;
    int r = q % 3840;
    int row = r >> 4, co = r & 15;
    const float* Wr; int pairs; int lrow;
    if (row < 48)       { Wr = Wr0; pairs = 3; lrow = row; }
    else if (row < 144) { Wr = Wr1; pairs = 6; lrow = row - 48; }
    else                { Wr = Wr2; pairs = 6; lrow = row - 144; }
    int pairIdx = lrow >> 4, c = lrow & 15;
    const float* base = Wr + (size_t)layer*pairs*4096 + (size_t)(pairIdx*256 + c*16)*16 + co;
    float s = 0.f;
    #pragma unroll
    for (int d = 0; d < 16; ++d) s += base[d*16];
    wrsum[q] = s;
}

__device__ __forceinline__ void ld_tables(const float* __restrict__ blob, float* CG, unsigned short* TB,
                                          unsigned char* TA, unsigned short* TC, int t){
    for (int i = t; i < 615; i += 512) CG[i] = blob[i];
    const unsigned short* bTB = (const unsigned short*)((const char*)blob + 2464);
    for (int i = t; i < 816; i += 512) TB[i] = bTB[i];
    const unsigned char* bTA = (const unsigned char*)((const char*)blob + 4096);
    if (t < 160) TA[t] = bTA[t];
    const unsigned short* bTC = (const unsigned short*)((const char*)blob + 4256);
    if (t < 160) TC[t] = bTC[t];
}

__device__ __forceinline__ void tfill_full(const float* __restrict__ A, const float* __restrict__ S,
                                           const float* __restrict__ CG, const unsigned short* __restrict__ TB,
                                           const unsigned char* __restrict__ TA, const unsigned short* __restrict__ TC,
                                           float* __restrict__ Tw, int lane){
    for (int idx = lane; idx < 816; idx += 64){
        unsigned tbv = TB[idx];
        int c = tbv & 15, st = (tbv>>4) & 255, ct = tbv >> 12;
        float s = 0.f;
        for (int q = 0; q < ct; ++q){
            int ab = TA[st+q];
            s += A[(ab>>4)*16 + c] * S[ab & 15] * CG[TC[st+q]];
        }
        Tw[idx] = s;
    }
}

__device__ __forceinline__ void tfill_diag(const float* __restrict__ M,
                                           const float* __restrict__ CG, const unsigned short* __restrict__ TB,
                                           const unsigned char* __restrict__ TA, const unsigned short* __restrict__ TC,
                                           float* __restrict__ Tw, int lane){
    for (int idx = lane; idx < 816; idx += 64){
        unsigned tbv = TB[idx];
        int c = tbv & 15, st = (tbv>>4) & 255, ct = tbv >> 12;
        float s = 0.f;
        for (int q = 0; q < ct; ++q){
            int ab = TA[st+q];
            s += M[(ab>>4)*16 + c] * M[(ab&15)*16 + c] * CG[TC[st+q]];
        }
        Tw[idx] = s;
    }
}

__device__ __forceinline__ float mix_out(const float* __restrict__ WT, const float* __restrict__ Tw, int o){
    int krow = o >> 4, co = o & 15;
    int l = krow == 0 ? 0 : (krow < 4 ? 1 : 2);
    int k = krow - (l==0?0:(l==1?1:4));
    int np = l==0?3:6;
    int tb = l==0?0:(l==1?48:336);
    int rb = l==0?0:(l==1?48:144);
    int dl = 2*l+1;
    float acc = 0.f;
    const float4* Wp = (const float4*)&WT[co*244 + rb];
    for (int pq = 0; pq < np; ++pq){
        const float4* Tp = (const float4*)&Tw[tb + (pq*dl + k)*16];
        float4 a0=Tp[0],a1=Tp[1],a2=Tp[2],a3=Tp[3];
        float4 b0=Wp[pq*4],b1=Wp[pq*4+1],b2=Wp[pq*4+2],b3=Wp[pq*4+3];
        acc += a0.x*b0.x+a0.y*b0.y+a0.z*b0.z+a0.w*b0.w
             + a1.x*b1.x+a1.y*b1.y+a1.z*b1.z+a1.w*b1.w
             + a2.x*b2.x+a2.y*b2.y+a2.z*b2.z+a2.w*b2.w
             + a3.x*b3.x+a3.y*b3.y+a3.z*b3.z+a3.w*b3.w;
    }
    return acc;
}

// K1: layer-0 rel. 8 nodes/block, wave per node. Also emits sphx to ws.
__global__ __launch_bounds__(512) void k_rel0(const float* __restrict__ v0, const float* __restrict__ v1,
                                              const float* __restrict__ v2, const float* __restrict__ rel_pos,
                                              const float* __restrict__ blob, const float* __restrict__ wrsumL,
                                              float* __restrict__ sphx_ws, float* __restrict__ rel){
    __shared__ float CG[616];
    __shared__ unsigned short TB[816];
    __shared__ unsigned char TA[160];
    __shared__ unsigned short TC[160];
    __shared__ float WT[16*244];
    __shared__ float AL[8][144];
    __shared__ float SX[8][12];
    __shared__ __align__(16) float TS[8][816];
    int t = threadIdx.x, w = t >> 6, lane = t & 63;
    int node0 = blockIdx.x * 8, node = node0 + w;
    ld_tables(blob, CG, TB, TA, TC, t);
    for (int i = t; i < 3840; i += 512) WT[(i&15)*244 + (i>>4)] = wrsumL[i];
    for (int i = t; i < 1152; i += 512){
        int n = i/144, o = i%144, nd = node0+n;
        float v;
        if (o < 16)      v = v0[(size_t)nd*16 + o];
        else if (o < 64) v = v1[(size_t)nd*48 + (o-16)];
        else             v = v2[(size_t)nd*80 + (o-64)];
        AL[n][o] = v;
    }
    {
        const float* rp = rel_pos + (size_t)node * (NN*3);
        float a[9];
        #pragma unroll
        for (int i = 0; i < 9; ++i) a[i] = 0.f;
        #pragma unroll
        for (int rr = 0; rr < 2; ++rr){
            int j = lane + rr*64;
            float x = rp[j*3], y = rp[j*3+1], z = rp[j*3+2];
            float rn = sqrtf(x*x+y*y+z*z) + 1e-6f;
            x /= rn; y /= rn; z /= rn;
            a[0] += 0.28209479f;
            a[1] += 0.48860251f*y; a[2] += 0.48860251f*z; a[3] += 0.48860251f*x;
            a[4] += 1.09254843f*x*y; a[5] += 1.09254843f*y*z;
            a[6] += 0.31539157f*(3.f*z*z-1.f);
            a[7] += 1.09254843f*x*z; a[8] += 0.54627422f*(x*x-y*y);
        }
        #pragma unroll
        for (int i = 0; i < 9; ++i){
            float vv = a[i];
            for (int off = 32; off; off >>= 1) vv += __shfl_down(vv, off, 64);
            if (lane == 0){ SX[w][i] = vv; sphx_ws[(size_t)node*9 + i] = vv; }
        }
    }
    __syncthreads();
    tfill_full(&AL[w][0], &SX[w][0], CG, TB, TA, TC, &TS[w][0], lane);
    __syncthreads();
    float* relw = rel + (size_t)node * 144;
    for (int o = lane; o < 144; o += 64) relw[o] = mix_out(WT, &TS[w][0], o);
}

// K2/K4: message pass + diag CG + Wn mix + per-block partial sums.
// Rolling 1-round register prefetch (3 float4 = 12 VGPRs live).
__global__ __launch_bounds__(512) void k_mp(const float* __restrict__ norms, const float* __restrict__ rel,
                                            const float* __restrict__ blob,
                                            const float* __restrict__ Wn0, const float* __restrict__ Wn1,
                                            const float* __restrict__ Wn2, int layer,
                                            float* __restrict__ nl, float* __restrict__ part){
    __shared__ float CG[616];
    __shared__ unsigned short TB[816];
    __shared__ unsigned char TA[160];
    __shared__ unsigned short TC[160];
    __shared__ float WT[16*244];
    __shared__ unsigned char C4[8][128];
    __shared__ float MP[8][144];
    __shared__ __align__(16) float TS[8][816];
    __shared__ float RED[24];
    int t = threadIdx.x, w = t >> 6, lane = t & 63;
    int node0 = blockIdx.x * 8, node = node0 + w;
    int b = node0 >> 7;
    ld_tables(blob, CG, TB, TA, TC, t);
    for (int i = t; i < 768;  i += 512) WT[(i&15)*244 + (i>>4)]        = Wn0[(size_t)layer*768  + i];
    for (int i = t; i < 1536; i += 512) WT[(i&15)*244 + 48  + (i>>4)]  = Wn1[(size_t)layer*1536 + i];
    for (int i = t; i < 1536; i += 512) WT[(i&15)*244 + 144 + (i>>4)]  = Wn2[(size_t)layer*1536 + i];
    for (int i = t; i < 1024; i += 512){
        int n = i >> 7, j = i & 127;
        C4[n][j] = (norms[(size_t)(node0+n)*NN + j] < 0.5f) ? 1 : 0;
    }
    const float4* r4 = (const float4*)(rel + (size_t)b * NN * 144);
    // round 0 prefetch (registers): 3 float4 per thread max
    float4 rA = r4[t];
    float4 rB = r4[512 + t];
    float4 rC = (t < 128) ? r4[1024 + t] : make_float4(0.f,0.f,0.f,0.f);
    float a0 = 0.f, a1 = 0.f, a2 = 0.f;
    float4* s4 = (float4*)&TS[0][0];
    #pragma unroll
    for (int r = 0; r < 4; ++r){
        __syncthreads();
        s4[t] = rA; s4[512+t] = rB; if (t < 128) s4[1024+t] = rC;
        __syncthreads();
        if (r < 3){
            rA = r4[(r+1)*1152 + t];
            rB = r4[(r+1)*1152 + 512 + t];
            if (t < 128) rC = r4[(r+1)*1152 + 1024 + t];
        }
        const unsigned* cw = (const unsigned*)&C4[w][r*32];
        const float* base = &TS[0][0];
        #pragma unroll
        for (int jq = 0; jq < 8; ++jq){
            unsigned cword = cw[jq];
            #pragma unroll
            for (int jb = 0; jb < 4; ++jb){
                float cn = (float)((cword >> (jb*8)) & 255u);
                const float* row = base + (jq*4+jb)*144;
                a0 += cn * row[lane];
                a1 += cn * row[64 + lane];
                if (lane < 16) a2 += cn * row[128 + lane];
            }
        }
    }
    __syncthreads();
    MP[w][lane] = a0; MP[w][64+lane] = a1; if (lane < 16) MP[w][128+lane] = a2;
    __syncthreads();
    tfill_diag(&MP[w][0], CG, TB, TA, TC, &TS[w][0], lane);
    __syncthreads();
    float pz0 = 0.f, pz1 = 0.f, pz2 = 0.f;
    float* nlw = nl + (size_t)node * 144;
    for (int o = lane; o < 144; o += 64){
        float acc = mix_out(WT, &TS[w][0], o);
        nlw[o] = acc;
        float sq = acc*acc;
        int krow = o >> 4;
        if (krow == 0) pz0 += sq; else if (krow < 4) pz1 += sq; else pz2 += sq;
    }
    for (int off = 32; off; off >>= 1){
        pz0 += __shfl_down(pz0, off, 64);
        pz1 += __shfl_down(pz1, off, 64);
        pz2 += __shfl_down(pz2, off, 64);
    }
    if (lane == 0){ RED[w] = pz0; RED[8+w] = pz1; RED[16+w] = pz2; }
    __syncthreads();
    if (t < 3){
        float s = 0.f;
        #pragma unroll
        for (int q = 0; q < 8; ++q) s += RED[t*8 + q];
        part[blockIdx.x*4 + t] = s;
    }
}

// K3: normalize layer0 + scalars out + layer-1 rel.
__global__ __launch_bounds__(512) void k_eb(const float* __restrict__ blob, const float* __restrict__ wrsumL1,
                                            const float* __restrict__ part, const float* __restrict__ nl,
                                            const float* __restrict__ sphx_ws, float* __restrict__ rel,
                                            float* __restrict__ out){
    __shared__ float CG[616];
    __shared__ unsigned short TB[816];
    __shared__ unsigned char TA[160];
    __shared__ unsigned short TC[160];
    __shared__ float WT[16*244];
    __shared__ float AL[8][144];
    __shared__ float SX[8][12];
    __shared__ __align__(16) float TS[8][816];
    __shared__ float RED[24];
    __shared__ float SC[3];
    int t = threadIdx.x, w = t >> 6, lane = t & 63;
    int node0 = blockIdx.x * 8, node = node0 + w;
    ld_tables(blob, CG, TB, TA, TC, t);
    for (int i = t; i < 3840; i += 512) WT[(i&15)*244 + (i>>4)] = wrsumL1[i];
    {
        float q0 = part[t*4], q1 = part[t*4+1], q2 = part[t*4+2];
        for (int off = 32; off; off >>= 1){
            q0 += __shfl_down(q0, off, 64);
            q1 += __shfl_down(q1, off, 64);
            q2 += __shfl_down(q2, off, 64);
        }
        if (lane == 0){ RED[w] = q0; RED[8+w] = q1; RED[16+w] = q2; }
    }
    __syncthreads();
    if (t < 3){
        float s = 0.f;
        #pragma unroll
        for (int q = 0; q < 8; ++q) s += RED[t*8 + q];
        SC[t] = 16.f / ((2*t+1) * sqrtf(s));
    }
    __syncthreads();
    float sc0 = SC[0], sc1 = SC[1], sc2 = SC[2];
    for (int i = t; i < 1152; i += 512){
        int n = i/144, o = i%144, krow = o >> 4;
        float scl = krow == 0 ? sc0 : (krow < 4 ? sc1 : sc2);
        AL[n][o] = nl[(size_t)(node0+n)*144 + o] * scl;
    }
    if (t < 72) SX[t/9][t%9] = sphx_ws[(size_t)node0*9 + t];
    __syncthreads();
    if (t < 128){
        int n = t >> 4, c = t & 15;
        float s0 = AL[n][c];
        float sn0 = s0*s0, sn1 = 0.f, sn2 = 0.f;
        #pragma unroll
        for (int k = 0; k < 3; ++k){ float v = AL[n][16 + k*16 + c]; sn1 += v*v; }
        #pragma unroll
        for (int k = 0; k < 5; ++k){ float v = AL[n][64 + k*16 + c]; sn2 += v*v; }
        float* ob = out + (size_t)(node0+n)*128;
        ob[c] = s0; ob[16+c] = sn0; ob[32+c] = sn1; ob[48+c] = sn2;
    }
    tfill_full(&AL[w][0], &SX[w][0], CG, TB, TA, TC, &TS[w][0], lane);
    __syncthreads();
    float* relw = rel + (size_t)node * 144;
    for (int o = lane; o < 144; o += 64) relw[o] = mix_out(WT, &TS[w][0], o);
}

// K5: normalize layer1 + scalars out.
__global__ __launch_bounds__(512) void k_e2(const float* __restrict__ part, const float* __restrict__ nl,
                                            float* __restrict__ out){
    __shared__ float RED[24];
    __shared__ float SC[3];
    __shared__ float VV[8][144];
    int t = threadIdx.x, w = t >> 6, lane = t & 63;
    int node0 = blockIdx.x * 8;
    {
        float q0 = part[t*4], q1 = part[t*4+1], q2 = part[t*4+2];
        for (int off = 32; off; off >>= 1){
            q0 += __shfl_down(q0, off, 64);
            q1 += __shfl_down(q1, off, 64);
            q2 += __shfl_down(q2, off, 64);
        }
        if (lane == 0){ RED[w] = q0; RED[8+w] = q1; RED[16+w] = q2; }
    }
    __syncthreads();
    if (t < 3){
        float s = 0.f;
        #pragma unroll
        for (int q = 0; q < 8; ++q) s += RED[t*8 + q];
        SC[t] = 16.f / ((2*t+1) * sqrtf(s));
    }
    __syncthreads();
    float sc0 = SC[0], sc1 = SC[1], sc2 = SC[2];
    for (int i = t; i < 1152; i += 512){
        int n = i/144, o = i%144, krow = o >> 4;
        float scl = krow == 0 ? sc0 : (krow < 4 ? sc1 : sc2);
        VV[n][o] = nl[(size_t)(node0+n)*144 + o] * scl;
    }
    __syncthreads();
    if (t < 128){
        int n = t >> 4, c = t & 15;
        float s0 = VV[n][c];
        float sn0 = s0*s0, sn1 = 0.f, sn2 = 0.f;
        #pragma unroll
        for (int k = 0; k < 3; ++k){ float v = VV[n][16 + k*16 + c]; sn1 += v*v; }
        #pragma unroll
        for (int k = 0; k < 5; ++k){ float v = VV[n][64 + k*16 + c]; sn2 += v*v; }
        float* ob = out + (size_t)(node0+n)*128 + 64;
        ob[c] = s0; ob[16+c] = sn0; ob[32+c] = sn1; ob[48+c] = sn2;
    }
}

extern "C" void kernel_launch(void* const* d_in, const int* in_sizes, int n_in,
                              void* d_out, int out_size, void* d_ws, size_t ws_size,
                              hipStream_t stream){
    const float* v0      = (const float*)d_in[0];
    const float* v1      = (const float*)d_in[1];
    const float* v2      = (const float*)d_in[2];
    const float* rel_pos = (const float*)d_in[3];
    const float* norms   = (const float*)d_in[4];
    const float* Wr0     = (const float*)d_in[5];
    const float* Wr1     = (const float*)d_in[6];
    const float* Wr2     = (const float*)d_in[7];
    const float* Wn0     = (const float*)d_in[8];
    const float* Wn1     = (const float*)d_in[9];
    const float* Wn2     = (const float*)d_in[10];
    float* out = (float*)d_out;
    float* ws  = (float*)d_ws;

    // ws layout (float offsets)
    float* blob  = ws + 0;        // 1152 (4608 B: CG+TB+TA+TC)
    float* wrsum = ws + 1152;     // 7680
    float* sphx  = ws + 8832;     // 4096*9 = 36864
    float* rel   = ws + 45696;    // 4096*144 = 589824
    float* nl    = ws + 635520;   // 4096*144 = 589824
    float* part  = ws + 1225344;  // 512*4 = 2048

    k_setup<<<16, 512, 0, stream>>>(Wr0, Wr1, Wr2, blob, wrsum);
    k_rel0 <<<512, 512, 0, stream>>>(v0, v1, v2, rel_pos, blob, wrsum, sphx, rel);
    k_mp   <<<512, 512, 0, stream>>>(norms, rel, blob, Wn0, Wn1, Wn2, 0, nl, part);
    k_eb   <<<512, 512, 0, stream>>>(blob, wrsum + 3840, part, nl, sphx, rel, out);
    k_mp   <<<512, 512, 0, stream>>>(norms, rel, blob, Wn0, Wn1, Wn2, 1, nl, part);
    k_e2   <<<512, 512, 0, stream>>>(part, nl, out);
}

// Round 8
// 203.346 us; speedup vs baseline: 2.1773x; 1.5498x over previous
//
#include <hip/hip_runtime.h>

#define NN 128

// 15 (l, pair) entries in reference order:
// l=0: (0,0),(1,1),(2,2)
// l=1: (0,1),(1,0),(1,1),(1,2),(2,1),(2,2)
// l=2: (0,2),(1,1),(1,2),(2,0),(2,1),(2,2)
__constant__ int E_l [15] = {0,0,0, 1,1,1,1,1,1, 2,2,2,2,2,2};
__constant__ int E_l1[15] = {0,1,2, 0,1,1,1,2,2, 0,1,1,2,2,2};
__constant__ int E_l2[15] = {0,1,2, 1,0,1,2,1,2, 2,1,2,0,1,2};
__constant__ int E_cg[15] = {0,1,10, 35,44,53,80,125,170, 245,270,315,390,415,490};
__constant__ int E_t [15] = {0,16,32, 48,96,144,192,240,288, 336,416,496,576,656,736};

__device__ __forceinline__ double dfact(int n){
    const double F[9] = {1.0,1.0,2.0,6.0,24.0,120.0,720.0,5040.0,40320.0};
    return F[n];
}

__device__ float cg_single(int j1,int m1,int j2,int m2,int j,int m){
    if (m1 + m2 != m) return 0.0f;
    double pre = sqrt((2.0*j+1.0)*dfact(j+j1-j2)*dfact(j-j1+j2)*dfact(j1+j2-j)/dfact(j1+j2+j+1));
    pre *= sqrt(dfact(j+m)*dfact(j-m)*dfact(j1-m1)*dfact(j1+m1)*dfact(j2-m2)*dfact(j2+m2));
    int k0 = 0;
    if (j2-j-m1 > k0) k0 = j2-j-m1;
    if (j1+m2-j > k0) k0 = j1+m2-j;
    int k1 = j1+j2-j;
    if (j1-m1 < k1) k1 = j1-m1;
    if (j2+m2 < k1) k1 = j2+m2;
    double s = 0.0;
    for (int k = k0; k <= k1; ++k){
        double d = dfact(k)*dfact(j1+j2-j-k)*dfact(j1-m1-k)*dfact(j2+m2-k)*dfact(j-j2+m1+k)*dfact(j-j1-m2+k);
        s += ((k & 1) ? -1.0 : 1.0) / d;
    }
    return (float)(pre * s);
}

// blob (float* base) layout: CG f32[615] @0 | TB u16[816] @byte 2464 | TA u8[160] @4096 | TC u16[160] @4256
// TB packs c(4) | st(8)<<4 | ct(4)<<12 ; TA packs a_idx(4)<<4 | b_idx(4) ; TC = CG flat index.

// k_setup: bid 0 -> build CG + term tables; bid 1..15 -> wrsum (sum_d of Wr rows)
__global__ __launch_bounds__(512) void k_setup(const float* __restrict__ Wr0, const float* __restrict__ Wr1,
                                               const float* __restrict__ Wr2,
                                               float* __restrict__ blob, float* __restrict__ wrsum){
    int bx = blockIdx.x, t = threadIdx.x;
    if (bx == 0){
        for (int idx = t; idx < 615; idx += 512){
            int e = 0;
            while (e < 14 && idx >= E_cg[e+1]) e++;
            int l = E_l[e], l1 = E_l1[e], l2 = E_l2[e];
            int local = idx - E_cg[e];
            int dl = 2*l+1, d2 = 2*l2+1;
            int k  = local % dl;
            int r  = local / dl;
            int u  = r % d2;
            int i1 = r / d2;
            blob[idx] = cg_single(l1, i1-l1, l2, u-l2, l, k-l);
        }
        if (t == 0){
            unsigned short* bTB = (unsigned short*)((char*)blob + 2464);
            unsigned char*  bTA = (unsigned char*)((char*)blob + 4096);
            unsigned short* bTC = (unsigned short*)((char*)blob + 4256);
            const int abase[3] = {0,1,4};
            int nt = 0;
            for (int e = 0; e < 15; ++e){
                int l = E_l[e], l1 = E_l1[e], l2 = E_l2[e];
                int dl = 2*l+1, d2 = 2*l2+1;
                for (int k = 0; k < dl; ++k){
                    int st = nt;
                    for (int m = 0; m < 2*l1+1; ++m){
                        int u = k - l + l1 + l2 - m;
                        if (u >= 0 && u <= 2*l2){
                            bTA[nt] = (unsigned char)(((abase[l1]+m)<<4) | (abase[l2]+u));
                            bTC[nt] = (unsigned short)(E_cg[e] + (m*d2+u)*dl + k);
                            nt++;
                        }
                    }
                    int ct = nt - st;
                    for (int c = 0; c < 16; ++c)
                        bTB[E_t[e] + k*16 + c] = (unsigned short)(c | (st<<4) | (ct<<12));
                }
            }
        }
        return;
    }
    int q = (bx-1)*512 + t;          // 7680 total
    int layer = q / 3840;
    int r = q % 3840;
    int row = r >> 4, co = r & 15;
    const float* Wr; int pairs; int lrow;
    if (row < 48)       { Wr = Wr0; pairs = 3; lrow = row; }
    else if (row < 144) { Wr = Wr1; pairs = 6; lrow = row - 48; }
    else                { Wr = Wr2; pairs = 6; lrow = row - 144; }
    int pairIdx = lrow >> 4, c = lrow & 15;
    const float* base = Wr + (size_t)layer*pairs*4096 + (size_t)(pairIdx*256 + c*16)*16 + co;
    float s = 0.f;
    #pragma unroll
    for (int d = 0; d < 16; ++d) s += base[d*16];
    wrsum[q] = s;
}

__device__ __forceinline__ void ld_tables(const float* __restrict__ blob, float* CG, unsigned short* TB,
                                          unsigned char* TA, unsigned short* TC, int t){
    for (int i = t; i < 615; i += 512) CG[i] = blob[i];
    const unsigned short* bTB = (const unsigned short*)((const char*)blob + 2464);
    for (int i = t; i < 816; i += 512) TB[i] = bTB[i];
    const unsigned char* bTA = (const unsigned char*)((const char*)blob + 4096);
    if (t < 160) TA[t] = bTA[t];
    const unsigned short* bTC = (const unsigned short*)((const char*)blob + 4256);
    if (t < 160) TC[t] = bTC[t];
}

__device__ __forceinline__ void tfill_full(const float* __restrict__ A, const float* __restrict__ S,
                                           const float* __restrict__ CG, const unsigned short* __restrict__ TB,
                                           const unsigned char* __restrict__ TA, const unsigned short* __restrict__ TC,
                                           float* __restrict__ Tw, int lane){
    #pragma unroll 1
    for (int idx = lane; idx < 816; idx += 64){
        unsigned tbv = TB[idx];
        int c = tbv & 15, st = (tbv>>4) & 255, ct = tbv >> 12;
        float s = 0.f;
        for (int q = 0; q < ct; ++q){
            int ab = TA[st+q];
            s += A[(ab>>4)*16 + c] * S[ab & 15] * CG[TC[st+q]];
        }
        Tw[idx] = s;
    }
}

__device__ __forceinline__ void tfill_diag(const float* __restrict__ M,
                                           const float* __restrict__ CG, const unsigned short* __restrict__ TB,
                                           const unsigned char* __restrict__ TA, const unsigned short* __restrict__ TC,
                                           float* __restrict__ Tw, int lane){
    #pragma unroll 1
    for (int idx = lane; idx < 816; idx += 64){
        unsigned tbv = TB[idx];
        int c = tbv & 15, st = (tbv>>4) & 255, ct = tbv >> 12;
        float s = 0.f;
        for (int q = 0; q < ct; ++q){
            int ab = TA[st+q];
            s += M[(ab>>4)*16 + c] * M[(ab&15)*16 + c] * CG[TC[st+q]];
        }
        Tw[idx] = s;
    }
}

__device__ __forceinline__ float mix_out(const float* __restrict__ WT, const float* __restrict__ Tw, int o){
    int krow = o >> 4, co = o & 15;
    int l = krow == 0 ? 0 : (krow < 4 ? 1 : 2);
    int k = krow - (l==0?0:(l==1?1:4));
    int np = l==0?3:6;
    int tb = l==0?0:(l==1?48:336);
    int rb = l==0?0:(l==1?48:144);
    int dl = 2*l+1;
    float acc = 0.f;
    const float4* Wp = (const float4*)&WT[co*244 + rb];
    #pragma unroll 1
    for (int pq = 0; pq < np; ++pq){
        const float4* Tp = (const float4*)&Tw[tb + (pq*dl + k)*16];
        float4 a0=Tp[0],a1=Tp[1],a2=Tp[2],a3=Tp[3];
        float4 b0=Wp[pq*4],b1=Wp[pq*4+1],b2=Wp[pq*4+2],b3=Wp[pq*4+3];
        acc += a0.x*b0.x+a0.y*b0.y+a0.z*b0.z+a0.w*b0.w
             + a1.x*b1.x+a1.y*b1.y+a1.z*b1.z+a1.w*b1.w
             + a2.x*b2.x+a2.y*b2.y+a2.z*b2.z+a2.w*b2.w
             + a3.x*b3.x+a3.y*b3.y+a3.z*b3.z+a3.w*b3.w;
    }
    return acc;
}

// K1: layer-0 rel. 8 nodes/block, wave per node. Also emits sphx to ws.
__global__ __launch_bounds__(512) void k_rel0(const float* __restrict__ v0, const float* __restrict__ v1,
                                              const float* __restrict__ v2, const float* __restrict__ rel_pos,
                                              const float* __restrict__ blob, const float* __restrict__ wrsumL,
                                              float* __restrict__ sphx_ws, float* __restrict__ rel){
    __shared__ float CG[616];
    __shared__ unsigned short TB[816];
    __shared__ unsigned char TA[160];
    __shared__ unsigned short TC[160];
    __shared__ float WT[16*244];
    __shared__ float AL[8][144];
    __shared__ float SX[8][12];
    __shared__ __align__(16) float TS[8][816];
    int t = threadIdx.x, w = t >> 6, lane = t & 63;
    int node0 = blockIdx.x * 8, node = node0 + w;
    ld_tables(blob, CG, TB, TA, TC, t);
    #pragma unroll 1
    for (int i = t; i < 3840; i += 512) WT[(i&15)*244 + (i>>4)] = wrsumL[i];
    #pragma unroll 1
    for (int i = t; i < 1152; i += 512){
        int n = i/144, o = i%144, nd = node0+n;
        float v;
        if (o < 16)      v = v0[(size_t)nd*16 + o];
        else if (o < 64) v = v1[(size_t)nd*48 + (o-16)];
        else             v = v2[(size_t)nd*80 + (o-64)];
        AL[n][o] = v;
    }
    {
        const float* rp = rel_pos + (size_t)node * (NN*3);
        float a[9];
        #pragma unroll
        for (int i = 0; i < 9; ++i) a[i] = 0.f;
        #pragma unroll
        for (int rr = 0; rr < 2; ++rr){
            int j = lane + rr*64;
            float x = rp[j*3], y = rp[j*3+1], z = rp[j*3+2];
            float rn = sqrtf(x*x+y*y+z*z) + 1e-6f;
            x /= rn; y /= rn; z /= rn;
            a[0] += 0.28209479f;
            a[1] += 0.48860251f*y; a[2] += 0.48860251f*z; a[3] += 0.48860251f*x;
            a[4] += 1.09254843f*x*y; a[5] += 1.09254843f*y*z;
            a[6] += 0.31539157f*(3.f*z*z-1.f);
            a[7] += 1.09254843f*x*z; a[8] += 0.54627422f*(x*x-y*y);
        }
        #pragma unroll
        for (int i = 0; i < 9; ++i){
            float vv = a[i];
            for (int off = 32; off; off >>= 1) vv += __shfl_down(vv, off, 64);
            if (lane == 0){ SX[w][i] = vv; sphx_ws[(size_t)node*9 + i] = vv; }
        }
    }
    __syncthreads();
    tfill_full(&AL[w][0], &SX[w][0], CG, TB, TA, TC, &TS[w][0], lane);
    __syncthreads();
    float* relw = rel + (size_t)node * 144;
    #pragma unroll 1
    for (int o = lane; o < 144; o += 64) relw[o] = mix_out(WT, &TS[w][0], o);
}

// K2/K4: message pass + diag CG + Wn mix + per-block partial sums.
// Register-diet: no outer unroll, inner unroll 4 -> live set fits under 128 VGPR, no scratch.
__global__ __launch_bounds__(512) void k_mp(const float* __restrict__ norms, const float* __restrict__ rel,
                                            const float* __restrict__ blob,
                                            const float* __restrict__ Wn0, const float* __restrict__ Wn1,
                                            const float* __restrict__ Wn2, int layer,
                                            float* __restrict__ nl, float* __restrict__ part){
    __shared__ float CG[616];
    __shared__ unsigned short TB[816];
    __shared__ unsigned char TA[160];
    __shared__ unsigned short TC[160];
    __shared__ float WT[16*244];
    __shared__ float C4[8][128];
    __shared__ float MP[8][144];
    __shared__ __align__(16) float TS[8][816];
    __shared__ float RED[24];
    int t = threadIdx.x, w = t >> 6, lane = t & 63;
    int node0 = blockIdx.x * 8, node = node0 + w;
    int b = node0 >> 7;
    ld_tables(blob, CG, TB, TA, TC, t);
    #pragma unroll 1
    for (int i = t; i < 768;  i += 512) WT[(i&15)*244 + (i>>4)]        = Wn0[(size_t)layer*768  + i];
    #pragma unroll 1
    for (int i = t; i < 1536; i += 512) WT[(i&15)*244 + 48  + (i>>4)]  = Wn1[(size_t)layer*1536 + i];
    #pragma unroll 1
    for (int i = t; i < 1536; i += 512) WT[(i&15)*244 + 144 + (i>>4)]  = Wn2[(size_t)layer*1536 + i];
    #pragma unroll 1
    for (int i = t; i < 1024; i += 512){
        int n = i >> 7, j = i & 127;
        C4[n][j] = (norms[(size_t)(node0+n)*NN + j] < 0.5f) ? 1.f : 0.f;
    }
    const float4* r4 = (const float4*)(rel + (size_t)b * NN * 144);
    // rolling 1-round register prefetch: 3 float4 live
    float4 rA = r4[t];
    float4 rB = r4[512 + t];
    float4 rC = (t < 128) ? r4[1024 + t] : make_float4(0.f,0.f,0.f,0.f);
    float a0 = 0.f, a1 = 0.f, a2 = 0.f;
    float4* s4 = (float4*)&TS[0][0];
    #pragma unroll 1
    for (int r = 0; r < 4; ++r){
        __syncthreads();
        s4[t] = rA; s4[512+t] = rB; if (t < 128) s4[1024+t] = rC;
        __syncthreads();
        if (r < 3){
            rA = r4[(r+1)*1152 + t];
            rB = r4[(r+1)*1152 + 512 + t];
            if (t < 128) rC = r4[(r+1)*1152 + 1024 + t];
        }
        #pragma unroll 4
        for (int jj = 0; jj < 32; ++jj){
            float cn = C4[w][r*32 + jj];
            const float* row = &TS[0][0] + jj*144;
            a0 += cn * row[lane];
            a1 += cn * row[64 + lane];
            if (lane < 16) a2 += cn * row[128 + lane];
        }
    }
    __syncthreads();
    MP[w][lane] = a0; MP[w][64+lane] = a1; if (lane < 16) MP[w][128+lane] = a2;
    __syncthreads();
    tfill_diag(&MP[w][0], CG, TB, TA, TC, &TS[w][0], lane);
    __syncthreads();
    float pz0 = 0.f, pz1 = 0.f, pz2 = 0.f;
    float* nlw = nl + (size_t)node * 144;
    #pragma unroll 1
    for (int o = lane; o < 144; o += 64){
        float acc = mix_out(WT, &TS[w][0], o);
        nlw[o] = acc;
        float sq = acc*acc;
        int krow = o >> 4;
        if (krow == 0) pz0 += sq; else if (krow < 4) pz1 += sq; else pz2 += sq;
    }
    for (int off = 32; off; off >>= 1){
        pz0 += __shfl_down(pz0, off, 64);
        pz1 += __shfl_down(pz1, off, 64);
        pz2 += __shfl_down(pz2, off, 64);
    }
    if (lane == 0){ RED[w] = pz0; RED[8+w] = pz1; RED[16+w] = pz2; }
    __syncthreads();
    if (t < 3){
        float s = 0.f;
        #pragma unroll
        for (int q = 0; q < 8; ++q) s += RED[t*8 + q];
        part[blockIdx.x*4 + t] = s;
    }
}

// K3: normalize layer0 + scalars out + layer-1 rel.
__global__ __launch_bounds__(512) void k_eb(const float* __restrict__ blob, const float* __restrict__ wrsumL1,
                                            const float* __restrict__ part, const float* __restrict__ nl,
                                            const float* __restrict__ sphx_ws, float* __restrict__ rel,
                                            float* __restrict__ out){
    __shared__ float CG[616];
    __shared__ unsigned short TB[816];
    __shared__ unsigned char TA[160];
    __shared__ unsigned short TC[160];
    __shared__ float WT[16*244];
    __shared__ float AL[8][144];
    __shared__ float SX[8][12];
    __shared__ __align__(16) float TS[8][816];
    __shared__ float RED[24];
    __shared__ float SC[3];
    int t = threadIdx.x, w = t >> 6, lane = t & 63;
    int node0 = blockIdx.x * 8, node = node0 + w;
    ld_tables(blob, CG, TB, TA, TC, t);
    #pragma unroll 1
    for (int i = t; i < 3840; i += 512) WT[(i&15)*244 + (i>>4)] = wrsumL1[i];
    {
        float q0 = part[t*4], q1 = part[t*4+1], q2 = part[t*4+2];
        for (int off = 32; off; off >>= 1){
            q0 += __shfl_down(q0, off, 64);
            q1 += __shfl_down(q1, off, 64);
            q2 += __shfl_down(q2, off, 64);
        }
        if (lane == 0){ RED[w] = q0; RED[8+w] = q1; RED[16+w] = q2; }
    }
    __syncthreads();
    if (t < 3){
        float s = 0.f;
        #pragma unroll
        for (int q = 0; q < 8; ++q) s += RED[t*8 + q];
        SC[t] = 16.f / ((2*t+1) * sqrtf(s));
    }
    __syncthreads();
    float sc0 = SC[0], sc1 = SC[1], sc2 = SC[2];
    #pragma unroll 1
    for (int i = t; i < 1152; i += 512){
        int n = i/144, o = i%144, krow = o >> 4;
        float scl = krow == 0 ? sc0 : (krow < 4 ? sc1 : sc2);
        AL[n][o] = nl[(size_t)(node0+n)*144 + o] * scl;
    }
    if (t < 72) SX[t/9][t%9] = sphx_ws[(size_t)node0*9 + t];
    __syncthreads();
    if (t < 128){
        int n = t >> 4, c = t & 15;
        float s0 = AL[n][c];
        float sn0 = s0*s0, sn1 = 0.f, sn2 = 0.f;
        #pragma unroll
        for (int k = 0; k < 3; ++k){ float v = AL[n][16 + k*16 + c]; sn1 += v*v; }
        #pragma unroll
        for (int k = 0; k < 5; ++k){ float v = AL[n][64 + k*16 + c]; sn2 += v*v; }
        float* ob = out + (size_t)(node0+n)*128;
        ob[c] = s0; ob[16+c] = sn0; ob[32+c] = sn1; ob[48+c] = sn2;
    }
    tfill_full(&AL[w][0], &SX[w][0], CG, TB, TA, TC, &TS[w][0], lane);
    __syncthreads();
    float* relw = rel + (size_t)node * 144;
    #pragma unroll 1
    for (int o = lane; o < 144; o += 64) relw[o] = mix_out(WT, &TS[w][0], o);
}

// K5: normalize layer1 + scalars out.
__global__ __launch_bounds__(512) void k_e2(const float* __restrict__ part, const float* __restrict__ nl,
                                            float* __restrict__ out){
    __shared__ float RED[24];
    __shared__ float SC[3];
    __shared__ float VV[8][144];
    int t = threadIdx.x, w = t >> 6, lane = t & 63;
    int node0 = blockIdx.x * 8;
    {
        float q0 = part[t*4], q1 = part[t*4+1], q2 = part[t*4+2];
        for (int off = 32; off; off >>= 1){
            q0 += __shfl_down(q0, off, 64);
            q1 += __shfl_down(q1, off, 64);
            q2 += __shfl_down(q2, off, 64);
        }
        if (lane == 0){ RED[w] = q0; RED[8+w] = q1; RED[16+w] = q2; }
    }
    __syncthreads();
    if (t < 3){
        float s = 0.f;
        #pragma unroll
        for (int q = 0; q < 8; ++q) s += RED[t*8 + q];
        SC[t] = 16.f / ((2*t+1) * sqrtf(s));
    }
    __syncthreads();
    float sc0 = SC[0], sc1 = SC[1], sc2 = SC[2];
    #pragma unroll 1
    for (int i = t; i < 1152; i += 512){
        int n = i/144, o = i%144, krow = o >> 4;
        float scl = krow == 0 ? sc0 : (krow < 4 ? sc1 : sc2);
        VV[n][o] = nl[(size_t)(node0+n)*144 + o] * scl;
    }
    __syncthreads();
    if (t < 128){
        int n = t >> 4, c = t & 15;
        float s0 = VV[n][c];
        float sn0 = s0*s0, sn1 = 0.f, sn2 = 0.f;
        #pragma unroll
        for (int k = 0; k < 3; ++k){ float v = VV[n][16 + k*16 + c]; sn1 += v*v; }
        #pragma unroll
        for (int k = 0; k < 5; ++k){ float v = VV[n][64 + k*16 + c]; sn2 += v*v; }
        float* ob = out + (size_t)(node0+n)*128 + 64;
        ob[c] = s0; ob[16+c] = sn0; ob[32+c] = sn1; ob[48+c] = sn2;
    }
}

extern "C" void kernel_launch(void* const* d_in, const int* in_sizes, int n_in,
                              void* d_out, int out_size, void* d_ws, size_t ws_size,
                              hipStream_t stream){
    const float* v0      = (const float*)d_in[0];
    const float* v1      = (const float*)d_in[1];
    const float* v2      = (const float*)d_in[2];
    const float* rel_pos = (const float*)d_in[3];
    const float* norms   = (const float*)d_in[4];
    const float* Wr0     = (const float*)d_in[5];
    const float* Wr1     = (const float*)d_in[6];
    const float* Wr2     = (const float*)d_in[7];
    const float* Wn0     = (const float*)d_in[8];
    const float* Wn1     = (const float*)d_in[9];
    const float* Wn2     = (const float*)d_in[10];
    float* out = (float*)d_out;
    float* ws  = (float*)d_ws;

    // ws layout (float offsets)
    float* blob  = ws + 0;        // 1152 (4608 B: CG+TB+TA+TC)
    float* wrsum = ws + 1152;     // 7680
    float* sphx  = ws + 8832;     // 4096*9 = 36864
    float* rel   = ws + 45696;    // 4096*144 = 589824
    float* nl    = ws + 635520;   // 4096*144 = 589824
    float* part  = ws + 1225344;  // 512*4 = 2048

    k_setup<<<16, 512, 0, stream>>>(Wr0, Wr1, Wr2, blob, wrsum);
    k_rel0 <<<512, 512, 0, stream>>>(v0, v1, v2, rel_pos, blob, wrsum, sphx, rel);
    k_mp   <<<512, 512, 0, stream>>>(norms, rel, blob, Wn0, Wn1, Wn2, 0, nl, part);
    k_eb   <<<512, 512, 0, stream>>>(blob, wrsum + 3840, part, nl, sphx, rel, out);
    k_mp   <<<512, 512, 0, stream>>>(norms, rel, blob, Wn0, Wn1, Wn2, 1, nl, part);
    k_e2   <<<512, 512, 0, stream>>>(part, nl, out);
}